// Round 10
// baseline (155.505 us; speedup 1.0000x reference)
//
#include <hip/hip_runtime.h>
#include <hip/hip_fp16.h>
#include <math.h>

// Problem constants
#define NPIX   131072      // B*H*W = 32*64*64
#define KEMB   512
#define DDIM   64
#define HW     4096        // H*W
#define BSTRIDE 262144     // C*H*W

// d_out flat layout (float32): [loss(1) | out(8388608) | perplexity(1) | indices(131072)]
#define OUT_OFF  1
#define PERP_OFF 8388609
#define IDX_OFF  8388610

typedef __attribute__((ext_vector_type(8))) _Float16 f16x8;    // MFMA A/B frag (4 VGPRs)
typedef __attribute__((ext_vector_type(4))) float f32x4;       // MFMA C/D frag

// SESSION LEDGER (proven on this problem):
//  - R9 = 82us vq_main (total 153.5, best): f16 2-split K-loop, both tables
//    LDS-resident, LDS prefetch pipeline, med3/min top-2, build-after-barrier,
//    (1024,4), 1 block/CU, 16 waves, fence-LESS ticket finalize.
//  - __threadfence() was the R3/R4/R5 ~2x curse (L2 WB/INV storm). NEVER.
//  - Reg cap < 128 spills the K-loop (+50-80MB HBM scratch, R1/R2). Never.
//  - In-K-loop global fragment streams serialize on load latency (R3). Never.
//  - In-block table build = conflicted u16 scatters (R4). Never.
//  - Occupancy QUANTIZED: 65..128 regs -> 16 waves/CU; <=64 spills. 16 is max.
//  - FETCH 29.7MB < input 33.5MB: input is L3-resident across iters — phases
//    are L3-LATENCY-bound at 4 waves/SIMD, not HBM-BW-bound.
//  - R10 (this): +global_load_lds staging (no VGPR round-trip), +build loads
//    issued before staging DMA (overlap), +setprio(1) around MFMA cluster.
//    Distance values / candidate order / tie-breaks / loss chain unchanged.
//
// 2-split f16 scheme (absmax 0 in R2..R9): x = h + l/2048 + r, |r|<=2^-21|x|.
// l pre-scaled by 2^11 (exact pow2) stays in f16 normal range. Products kept:
// hh + (h*l'+l'*h)/2048; dropped terms ~1e-4 absolute, and the exact fp32
// top-2 rescore decides the final index.

// ws layout: [0,2048) int counts | [2048,4096) float hnorms | [4096] loss |
//            [4160] done_ctr | [8192,73728) eh_t (f16 high, frag-linear, 64KB) |
//            [73728,139264) el_t (f16 low pre-scaled by 2^11, frag-linear, 64KB)
// frag-linear: idx = ct*1024 + ks*512 + (quad*16+col)*8 + j  (R5-proven), so
// vq_main stages both tables with straight linear 16B/lane DMA.
__global__ void vq_init(const float* __restrict__ emb, int* __restrict__ counts,
                        float* __restrict__ hnorms, float* __restrict__ loss_acc,
                        int* __restrict__ done_ctr,
                        unsigned short* __restrict__ eh_t,
                        unsigned short* __restrict__ el_t) {
    const int k = blockIdx.x;             // code
    const int c = threadIdx.x;            // channel
    const int ct = k >> 4, cl = k & 15;
    const int ks = c >> 5, qd = (c >> 3) & 3, j = c & 7;
    float x = emb[k * DDIM + c];
    _Float16 h = (_Float16)x;             // v_cvt_f16_f32, RTNE
    float r1 = x - (float)h;              // exact (Sterbenz)
    _Float16 l = (_Float16)(r1 * 2048.0f);
    const int dst = ct * 1024 + ks * 512 + (qd * 16 + cl) * 8 + j;
    ((_Float16*)eh_t)[dst] = h;
    ((_Float16*)el_t)[dst] = l;
    float s = x * x;
#pragma unroll
    for (int off = 1; off <= 32; off <<= 1) s += __shfl_xor(s, off, 64);
    if (c == 0) {
        hnorms[k] = 0.5f * s;
        counts[k] = 0;
        if (k == 0) { *loss_acc = 0.f; *done_ctr = 0; }
    }
}

// 256 blocks x 1024 threads, 1 block/CU, 16 waves (proven shape). LDS 132KB:
// both f16 tables resident -> K-loop is pure LDS + 12 MFMA/tile, barrier-free,
// software-pipelined. Staging is now direct L2->LDS DMA (global_load_lds) and
// the x build loads are issued FIRST so they drain under the staging DMA.
__global__ __launch_bounds__(1024, 4) void vq_main(
    const float* __restrict__ in, const float* __restrict__ emb,
    const unsigned short* __restrict__ eh_t, const unsigned short* __restrict__ el_t,
    const float* __restrict__ hnorms, int* __restrict__ counts,
    float* __restrict__ loss_acc, int* __restrict__ done_ctr,
    float* __restrict__ dout)
{
    __shared__ __align__(16) _Float16 eh_l[KEMB * DDIM];   // 64 KB
    __shared__ __align__(16) _Float16 el_l[KEMB * DDIM];   // 64 KB
    __shared__ __align__(16) float hn_lds[KEMB];           // 2 KB
    __shared__ int hist[KEMB];                             // 2 KB
    __shared__ float part[8];
    __shared__ int lastflag;

    const int t    = threadIdx.x;         // 0..1023
    const int lane = t & 63;
    const int wv   = t >> 6;              // wave id 0..15
    const int quad = lane >> 4;
    const int col  = lane & 15;
    const int b    = blockIdx.x >> 3;                        // 8 blocks per image
    const int p0   = ((blockIdx.x & 7) << 9) | (wv << 5);    // first of this wave's 32 px
    const float* xb = in + b * BSTRIDE;

    if (t < KEMB) hist[t] = 0;
    if (t < 128) ((float4*)hn_lds)[t] = ((const float4*)hnorms)[t];

    // ---- Issue the x build loads FIRST (32 regs): they drain from L3/HBM
    // while the staging DMA below runs. Converts happen after.
    float xv[2][2][8];
#pragma unroll
    for (int tt = 0; tt < 2; ++tt)
#pragma unroll
        for (int s = 0; s < 2; ++s) {
            const int ppb = p0 + tt * 16 + col;
            const int c0  = s * 32 + quad * 8;
#pragma unroll
            for (int j = 0; j < 8; ++j)
                xv[tt][s][j] = xb[(c0 + j) * HW + ppb];
        }

    // ---- Stage both tables into LDS via direct L2->LDS DMA (16B/lane, the
    // wave-uniform-base + lane*16 linear pattern global_load_lds requires).
    // No VGPR round-trip, no ds_write. __syncthreads drains vmcnt for the DMA.
#pragma unroll
    for (int i = 0; i < 4; ++i) {
        const int f = (t + i * 1024) * 8;   // halfword index, byte = 16*(t+i*1024)
        __builtin_amdgcn_global_load_lds((const __attribute__((address_space(1))) void*)((const _Float16*)eh_t + f),
                                         (__attribute__((address_space(3))) void*)&eh_l[f], 16, 0, 0);
        __builtin_amdgcn_global_load_lds((const __attribute__((address_space(1))) void*)((const _Float16*)el_t + f),
                                         (__attribute__((address_space(3))) void*)&el_l[f], 16, 0, 0);
    }

    // ---- Convert x to B-fragments (registers only) while the DMA completes.
    f16x8 xh[2][2], xl[2][2];
#pragma unroll
    for (int tt = 0; tt < 2; ++tt) {
#pragma unroll
        for (int s = 0; s < 2; ++s) {
            f16x8 vh, vl;
#pragma unroll
            for (int j = 0; j < 8; ++j) {
                float x = xv[tt][s][j];
                _Float16 h = (_Float16)x;
                float r1 = x - (float)h;
                vh[j] = h;
                vl[j] = (_Float16)(r1 * 2048.0f);
            }
            xh[tt][s] = vh; xl[tt][s] = vl;
        }
    }

    __syncthreads();   // tables + hn + hist ready; K-loop below is barrier-free

    // ---- K-loop over 32 code tiles — pure LDS + 12 MFMA per tile, barrier-
    // free, software-pipelined. Distance arithmetic bitwise == R9.
    float v1[2], v2[2]; int k1[2], k2[2];
#pragma unroll
    for (int tt = 0; tt < 2; ++tt) {
        v1[tt] = 3.402823466e38f; v2[tt] = 3.402823466e38f; k1[tt] = 0; k2[tt] = 0;
    }

    // Prologue: tile 0 fragments
    f16x8 Ah0 = *(const f16x8*)&eh_l[lane * 8];
    f16x8 Ah1 = *(const f16x8*)&eh_l[lane * 8 + 512];
    f16x8 Al0 = *(const f16x8*)&el_l[lane * 8];
    f16x8 Al1 = *(const f16x8*)&el_l[lane * 8 + 512];

    for (int ct = 0; ct < 32; ++ct) {
        f32x4 a0h = (f32x4){0.f, 0.f, 0.f, 0.f};
        f32x4 a0l = (f32x4){0.f, 0.f, 0.f, 0.f};
        f32x4 a1h = (f32x4){0.f, 0.f, 0.f, 0.f};
        f32x4 a1l = (f32x4){0.f, 0.f, 0.f, 0.f};
        __builtin_amdgcn_s_setprio(1);   // favor MFMA-entering waves (T5 regime:
                                         // barrier-free desynced waves)
        a0h = __builtin_amdgcn_mfma_f32_16x16x32_f16(Ah0, xh[0][0], a0h, 0, 0, 0);
        a0l = __builtin_amdgcn_mfma_f32_16x16x32_f16(Ah0, xl[0][0], a0l, 0, 0, 0);
        a0l = __builtin_amdgcn_mfma_f32_16x16x32_f16(Al0, xh[0][0], a0l, 0, 0, 0);
        a1h = __builtin_amdgcn_mfma_f32_16x16x32_f16(Ah0, xh[1][0], a1h, 0, 0, 0);
        a1l = __builtin_amdgcn_mfma_f32_16x16x32_f16(Ah0, xl[1][0], a1l, 0, 0, 0);
        a1l = __builtin_amdgcn_mfma_f32_16x16x32_f16(Al0, xh[1][0], a1l, 0, 0, 0);
        a0h = __builtin_amdgcn_mfma_f32_16x16x32_f16(Ah1, xh[0][1], a0h, 0, 0, 0);
        a0l = __builtin_amdgcn_mfma_f32_16x16x32_f16(Ah1, xl[0][1], a0l, 0, 0, 0);
        a0l = __builtin_amdgcn_mfma_f32_16x16x32_f16(Al1, xh[0][1], a0l, 0, 0, 0);
        a1h = __builtin_amdgcn_mfma_f32_16x16x32_f16(Ah1, xh[1][1], a1h, 0, 0, 0);
        a1l = __builtin_amdgcn_mfma_f32_16x16x32_f16(Ah1, xl[1][1], a1l, 0, 0, 0);
        a1l = __builtin_amdgcn_mfma_f32_16x16x32_f16(Al1, xh[1][1], a1l, 0, 0, 0);
        __builtin_amdgcn_s_setprio(0);

        // Prefetch next tile's fragments ((ct+1)&31 wraps harmlessly at 31);
        // the ds_reads drain under the select chain below.
        const int nbase = (((ct + 1) & 31) * 1024) + lane * 8;
        const f16x8 nAh0 = *(const f16x8*)&eh_l[nbase];
        const f16x8 nAh1 = *(const f16x8*)&eh_l[nbase + 512];
        const f16x8 nAl0 = *(const f16x8*)&el_l[nbase];
        const f16x8 nAl1 = *(const f16x8*)&el_l[nbase + 512];

        const f32x4 hn = *(const f32x4*)&hn_lds[ct * 16 + quad * 4];
#pragma unroll
        for (int r = 0; r < 4; ++r) {
            const int kk = ct * 16 + quad * 4 + r;
            // med3/min top-2 update — selection-identical to the strict-<
            // if/else chain (incl. ties -> keep incumbent / smaller index).
            {
                const float sc = hn[r] - (a0h[r] + a0l[r] * 4.8828125e-4f);
                const bool c1 = sc < v1[0];
                const bool c2 = sc < v2[0];
                const int nk2 = c1 ? k1[0] : (c2 ? kk : k2[0]);
                const int nk1 = c1 ? kk : k1[0];
                v2[0] = __builtin_amdgcn_fmed3f(v1[0], v2[0], sc);
                v1[0] = fminf(v1[0], sc);
                k1[0] = nk1; k2[0] = nk2;
            }
            {
                const float sc = hn[r] - (a1h[r] + a1l[r] * 4.8828125e-4f);
                const bool c1 = sc < v1[1];
                const bool c2 = sc < v2[1];
                const int nk2 = c1 ? k1[1] : (c2 ? kk : k2[1]);
                const int nk1 = c1 ? kk : k1[1];
                v2[1] = __builtin_amdgcn_fmed3f(v1[1], v2[1], sc);
                v1[1] = fminf(v1[1], sc);
                k1[1] = nk1; k2[1] = nk2;
            }
        }

        Ah0 = nAh0; Ah1 = nAh1; Al0 = nAl0; Al1 = nAl1;
    }

    // Cross-quad top-2 merge (lanes l, l^16, l^32 share pixel-col) — R0 verbatim
#pragma unroll
    for (int tt = 0; tt < 2; ++tt) {
#pragma unroll
        for (int off = 16; off <= 32; off <<= 1) {
            float w1 = __shfl_xor(v1[tt], off, 64); int j1 = __shfl_xor(k1[tt], off, 64);
            float w2 = __shfl_xor(v2[tt], off, 64); int j2 = __shfl_xor(k2[tt], off, 64);
            bool aF = (v1[tt] < w1) || (v1[tt] == w1 && k1[tt] < j1);
            float t1 = aF ? v1[tt] : w1;  int u1 = aF ? k1[tt] : j1;
            float tl = aF ? w1 : v1[tt];  int ul = aF ? j1 : k1[tt];      // loser of firsts
            bool bS = (v2[tt] < w2) || (v2[tt] == w2 && k2[tt] < j2);
            float tc = bS ? v2[tt] : w2;  int uc = bS ? k2[tt] : j2;      // better of seconds
            bool lS = (tl < tc) || (tl == tc && ul < uc);
            v1[tt] = t1; k1[tt] = u1;
            v2[tt] = lS ? tl : tc; k2[tt] = lS ? ul : uc;
        }
    }

    // Pixel q = lane&31; lanes l and l+32 handle the same pixel (tt = (l>>4)&1).
    const int q    = lane & 31;
    const int pp   = p0 + q;
    const int tsel = (lane >> 4) & 1;
    const int kA = tsel ? k1[1] : k1[0];
    const int kB = tsel ? k2[1] : k2[0];

    // Exact fp32 rescore, split: lanes<32 score kA, lanes>=32 score kB.
    // Streaming x loads — ops and order bitwise == the passing kernels.
    const int kMine = (lane < 32) ? kA : kB;
    const float4* eM = (const float4*)(emb + kMine * DDIM);
    float a0 = hn_lds[kMine], a1 = 0.f, a2 = 0.f, a3 = 0.f;
#pragma unroll
    for (int i = 0; i < 16; ++i) {
        float4 ea = eM[i];
        const int c = i * 4;
        float x0 = xb[(c + 0) * HW + pp];
        float x1 = xb[(c + 1) * HW + pp];
        float x2 = xb[(c + 2) * HW + pp];
        float x3 = xb[(c + 3) * HW + pp];
        a0 = fmaf(-x0, ea.x, a0);
        a1 = fmaf(-x1, ea.y, a1);
        a2 = fmaf(-x2, ea.z, a2);
        a3 = fmaf(-x3, ea.w, a3);
    }
    const float dMine = (a0 + a1) + (a2 + a3);
    const float dOth  = __shfl_xor(dMine, 32, 64);
    const float dA = (lane < 32) ? dMine : dOth;
    const float dB = (lane < 32) ? dOth  : dMine;
    const int myk = (dB < dA || (dB == dA && kB < kA)) ? kB : kA;

    float lsum = 0.f;
    if (lane < 32) {
        dout[IDX_OFF + b * HW + pp] = (float)myk;
        atomicAdd(&hist[myk], 1);
        const float4* qrow = (const float4*)(emb + myk * DDIM);
        float* ob = dout + OUT_OFF + b * BSTRIDE;
#pragma unroll
        for (int i = 0; i < 16; ++i) {
            float4 qv = qrow[i];
            const int c = i * 4;
            float x0 = xb[(c + 0) * HW + pp];   // L1-warm reload (just read above)
            float x1 = xb[(c + 1) * HW + pp];
            float x2 = xb[(c + 2) * HW + pp];
            float x3 = xb[(c + 3) * HW + pp];
            float d0 = qv.x - x0;
            float d1 = qv.y - x1;
            float d2 = qv.z - x2;
            float d3 = qv.w - x3;
            lsum += d0 * d0 + d1 * d1 + d2 * d2 + d3 * d3;
            ob[(c + 0) * HW + pp] = x0 + d0;    // reference rounding: x + (q - x)
            ob[(c + 1) * HW + pp] = x1 + d1;
            ob[(c + 2) * HW + pp] = x2 + d2;
            ob[(c + 3) * HW + pp] = x3 + d3;
        }
    }
    for (int off = 32; off > 0; off >>= 1) lsum += __shfl_down(lsum, off, 64);
    if (lane == 0) atomicAdd(loss_acc, lsum);

    __syncthreads();
    if (t < KEMB) {
        int v = hist[t];
        if (v) atomicAdd(&counts[t], v);
    }

    // ---- Fused finalize, fence-LESS (R6/R8/R9-proven): __syncthreads() drains
    // each wave's vmcnt before s_barrier, so this block's counts/loss atomics
    // have committed at the device coherence point before t==0 issues the
    // ticket. All cross-block state is atomic-only — no __threadfence.
    __syncthreads();
    if (t == 0) lastflag = (atomicAdd(done_ctr, 1) == 255) ? 1 : 0;
    __syncthreads();
    if (lastflag) {
        if (t < KEMB) {
            int cnt = atomicAdd(&counts[t], 0);   // device-coherent read
            float pa = (float)cnt / (float)NPIX;
            float v = pa * logf(pa + 1e-10f);
#pragma unroll
            for (int off = 1; off <= 32; off <<= 1) v += __shfl_xor(v, off, 64);
            if ((t & 63) == 0) part[t >> 6] = v;
        }
        __syncthreads();
        if (t == 0) {
            float s = 0.f;
#pragma unroll
            for (int i = 0; i < 8; ++i) s += part[i];
            dout[PERP_OFF] = expf(-s);
            dout[0] = 0.25f * atomicAdd(loss_acc, 0.0f) / 8388608.0f;
        }
    }
}

extern "C" void kernel_launch(void* const* d_in, const int* in_sizes, int n_in,
                              void* d_out, int out_size, void* d_ws, size_t ws_size,
                              hipStream_t stream) {
    const float* in  = (const float*)d_in[0];   // 8388608 elems
    const float* emb = (const float*)d_in[1];   // 32768 elems
    float* dout = (float*)d_out;
    int*   counts   = (int*)d_ws;
    float* hnorms   = (float*)((char*)d_ws + 2048);
    float* loss_acc = (float*)((char*)d_ws + 4096);
    int*   done_ctr = (int*)((char*)d_ws + 4160);
    unsigned short* eh_t = (unsigned short*)((char*)d_ws + 8192);
    unsigned short* el_t = eh_t + KEMB * DDIM;   // 64 KB scaled-l table

    vq_init<<<512, 64, 0, stream>>>(emb, counts, hnorms, loss_acc, done_ctr, eh_t, el_t);
    vq_main<<<256, 1024, 0, stream>>>(in, emb, eh_t, el_t, hnorms, counts, loss_acc, done_ctr, dout);
}